// Round 14
// baseline (837.874 us; speedup 1.0000x reference)
//
#include <hip/hip_runtime.h>
#include <cstdint>
#include <math.h>

// GREEN since r6. r12=529us (LDS b128 h-bcast + Un in LDS + 4-way butterfly).
// r13=650us REGRESSION: readlane h-bcast moved 32 DS ops to 128 serial VALU
// ops -> VALU has no slack. Lesson: delete work, don't relocate it.
// r12 counters show VGPR=132 with 128 U-floats live => allocator already
// serves U partly from AGPRs read directly by FMAs (gfx950 unified file).
// THIS ROUND (from r12 base): (1) Un -> registers/AGPRs too: deletes 64
// ds_read_b32/step, LDS 20KB->4KB; (2) dense logits via single difference
// reduction d = l1-l0 (softmax/logP are functions of d only): butterfly 24->12
// DS ops; p1=sig(d), p0=sig(-d), stable (exp(-|d|) underflows cleanly).
// DS/wave-step ~925 -> ~470 cyc.
// EMPIRICAL RULES: only __launch_bounds__(64,1) gives the full reg budget;
// OccupancyPercent is a gfx94x fallback (untrustworthy); decisions are
// rounding-robust (r2 f32-libm / r3 f64 / r4 cr-f32 / r7 rcp / r12 fast-exp:
// five variants, bit-identical streams).
// Locked-in: PRNG = partitionable threefry (key_t = tf((0,42),(0,t)); bits =
// o0^o1 of tf(key_t,(0,2s+cat))); f32 in/out; out = [4096*144][4096].

#define NSAMP 4096
#define NSTEP 144
#define HID 64
#define CPB 2            // chains per block (one wave)

typedef float v16f __attribute__((ext_vector_type(16)));

// ---- JAX threefry2x32 (20 rounds, key-inject every 4) ----
__device__ __forceinline__ void threefry2x32(uint32_t k0, uint32_t k1,
                                             uint32_t x0, uint32_t x1,
                                             uint32_t& o0, uint32_t& o1) {
  const uint32_t ks0 = k0, ks1 = k1, ks2 = k0 ^ k1 ^ 0x1BD11BDAu;
  x0 += ks0; x1 += ks1;
#define TF_ROUND(d) { x0 += x1; x1 = (x1 << (d)) | (x1 >> (32 - (d))); x1 ^= x0; }
  TF_ROUND(13) TF_ROUND(15) TF_ROUND(26) TF_ROUND(6)
  x0 += ks1; x1 += ks2 + 1u;
  TF_ROUND(17) TF_ROUND(29) TF_ROUND(16) TF_ROUND(24)
  x0 += ks2; x1 += ks0 + 2u;
  TF_ROUND(13) TF_ROUND(15) TF_ROUND(26) TF_ROUND(6)
  x0 += ks0; x1 += ks1 + 3u;
  TF_ROUND(17) TF_ROUND(29) TF_ROUND(16) TF_ROUND(24)
  x0 += ks1; x1 += ks2 + 4u;
  TF_ROUND(13) TF_ROUND(15) TF_ROUND(26) TF_ROUND(6)
  x0 += ks2; x1 += ks0 + 5u;
#undef TF_ROUND
  o0 = x0; o1 = x1;
}

// fast branch-free f32 transcendentals (raw v_exp_f32 / v_log_f32 / v_rcp_f32)
__device__ __forceinline__ float fsig(float x) {        // 1/(1+e^-x), stable
  return __builtin_amdgcn_rcpf(1.0f + __expf(-x));
}
__device__ __forceinline__ float ftanh(float x) {       // 1 - 2/(e^2x+1)
  const float e = __expf(2.0f * x);
  return 1.0f - 2.0f * __builtin_amdgcn_rcpf(e + 1.0f);
}

__global__ __launch_bounds__(64, 1) void vmc_kernel(
    const float* __restrict__ W, const float* __restrict__ U,
    const float* __restrict__ B, const float* __restrict__ Wd,
    const float* __restrict__ Bd, float* __restrict__ out) {
  const int j = threadIdx.x;           // hidden unit owned by this lane
  const int s_base = blockIdx.x * CPB; // first of 2 chains in this block

  __shared__ __align__(16) float2 hsh2[HID];      // h[unit] = {chain a, chain b}
  __shared__ uint2 kkeys[NSTEP];
  __shared__ float gsh[CPB * 2 * NSTEP];          // gumbels [c*288 + 2t + cat]

  // --- per-step keys: key_t = threefry((0,42),(0,t)) ---
#pragma unroll 1
  for (int t = j; t < NSTEP; t += HID) {
    uint32_t o0, o1;
    threefry2x32(0u, 42u, 0u, (uint32_t)t, o0, o1);
    kkeys[t].x = o0; kkeys[t].y = o1;
  }
  hsh2[j] = float2{0.0f, 0.0f};
  __syncthreads();

  // --- gumbels: EXACT path kept (f64 libm, one-time): bits = o0^o1 of
  // tf(key_t,(0,2s+cat)); u = bitcast(bits>>9|0x3f800000)-1 clamped tiny ---
#pragma unroll 1
  for (int id = j; id < CPB * 2 * NSTEP; id += HID) {
    const int c = id / 288;
    const int idx = id - c * 288;
    const uint2 kt = kkeys[idx >> 1];
    const uint32_t i = 2u * (uint32_t)(s_base + c) + (uint32_t)(idx & 1);
    uint32_t o0, o1;
    threefry2x32(kt.x, kt.y, 0u, i, o0, o1);
    const uint32_t bits = o0 ^ o1;
    union { uint32_t u; float f; } cv; cv.u = (bits >> 9) | 0x3F800000u;
    float uf = cv.f - 1.0f;
    uf = fmaxf(uf, 1.17549435e-38f);
    const float inner = (float)log((double)uf);
    gsh[id] = -(float)log((double)(-inner));
  }
  __syncthreads();

  // --- Uz, Ur, Un columns for unit j: all register/AGPR-resident (192) ---
  v16f uz0, uz1, uz2, uz3, ur0, ur1, ur2, ur3, un0, un1, un2, un3;
#define LOADB(v, r, off) \
  { _Pragma("unroll") for (int e = 0; e < 16; ++e) v[e] = U[((r)*16 + e)*192 + (off) + j]; }
  LOADB(uz0, 0, 0)    LOADB(uz1, 1, 0)    LOADB(uz2, 2, 0)    LOADB(uz3, 3, 0)
  LOADB(ur0, 0, 64)   LOADB(ur1, 1, 64)   LOADB(ur2, 2, 64)   LOADB(ur3, 3, 64)
  LOADB(un0, 0, 128)  LOADB(un1, 1, 128)  LOADB(un2, 2, 128)  LOADB(un3, 3, 128)
#undef LOADB

  const float b1z = B[192 + j], b1r = B[256 + j], b1n = B[320 + j];
  const float b0z = B[j],       b0r = B[64 + j],  b0n = B[128 + j];
  const float xW0z = W[j]       + b0z, xW1z = W[192 + j] + b0z;
  const float xW0r = W[64 + j]  + b0r, xW1r = W[256 + j] + b0r;
  const float xW0n = W[128 + j] + b0n, xW1n = W[320 + j] + b0n;
  const float wdd = Wd[2*j + 1] - Wd[2*j];   // dense difference column
  const float bdd = Bd[1] - Bd[0];

  float ha = 0.0f, hb_ = 0.0f;
  float logPa = 0.0f, logPb = 0.0f;
  float axz = b0z, axr = b0r, axn = b0n;  // t=0: x=0 -> xm = b[0]
  float bxz = b0z, bxr = b0r, bxn = b0n;
  // loop-carried dot accumulators; h_{-1}=0 -> dot=0 for t=0
  float hza = 0.f, hzb = 0.f, hra = 0.f, hrb = 0.f, hna = 0.f, hnb = 0.f;

  for (int t = 0; t < NSTEP; ++t) {
    // ---- gates from the PREVIOUS iteration's dot (software pipeline) ----
    {
      const float az = axz + (hza + b1z), ar = axr + (hra + b1r);
      const float zz = fsig(az), rr = fsig(ar);
      const float hh = ftanh(axn + rr * (hna + b1n));
      ha = zz * ha + (1.0f - zz) * hh;
    }
    {
      const float az = bxz + (hzb + b1z), ar = bxr + (hrb + b1r);
      const float zz = fsig(az), rr = fsig(ar);
      const float hh = ftanh(bxn + rr * (hnb + b1n));
      hb_ = zz * hb_ + (1.0f - zz) * hh;
    }
    hsh2[j] = float2{ha, hb_};   // single wave: LDS ops in program order

    // ---- dense: single difference-reduction per chain ----
    // d = sum_k h_k*(wd1_k - wd0_k) + (bd1-bd0); softmax/logP depend on d only
    float da = ha * wdd, db = hb_ * wdd;
#pragma unroll
    for (int m = 1; m < 64; m <<= 1) {
      da += __shfl_xor(da, m, 64);
      db += __shfl_xor(db, m, 64);
    }
    int sma, smb;
    {
      const float d = da + bdd;
      const float p1 = fsig(d), p0 = fsig(-d);     // stable at |d| large
      const float lp0 = __logf(1e-10f + p0);
      const float lp1 = __logf(1e-10f + p1);
      const float g0 = gsh[2*t], g1 = gsh[2*t + 1];
      sma = (lp1 + g1) > (lp0 + g0);
      logPa += sma ? lp1 : lp0;
      axz = sma ? xW1z : xW0z;
      axr = sma ? xW1r : xW0r;
      axn = sma ? xW1n : xW0n;
    }
    {
      const float d = db + bdd;
      const float p1 = fsig(d), p0 = fsig(-d);
      const float lp0 = __logf(1e-10f + p0);
      const float lp1 = __logf(1e-10f + p1);
      const float g0 = gsh[288 + 2*t], g1 = gsh[288 + 2*t + 1];
      smb = (lp1 + g1) > (lp0 + g0);
      logPb += smb ? lp1 : lp0;
      bxz = smb ? xW1z : xW0z;
      bxr = smb ? xW1r : xW0r;
      bxn = smb ? xW1n : xW0n;
    }
    if (j == 0) {
      out[(s_base + 0) * NSTEP + t] = sma ? 1.0f : 0.0f;
      out[(s_base + 1) * NSTEP + t] = smb ? 1.0f : 0.0f;
    }

    // ---- dot for NEXT step: hm = h_t @ U, k-ascending FMA from 0; h from
    // LDS b128 broadcast (r12 form), U entirely register/AGPR-resident ----
    hza = 0.f; hzb = 0.f; hra = 0.f; hrb = 0.f; hna = 0.f; hnb = 0.f;
#define DOTB(uzv, urv, unv, base) \
    { _Pragma("unroll") for (int e = 0; e < 16; e += 2) { \
        const float4 hv = *(const float4*)&hsh2[(base) + e]; \
        hza = __builtin_fmaf(hv.x, uzv[e],   hza); hzb = __builtin_fmaf(hv.y, uzv[e],   hzb); \
        hra = __builtin_fmaf(hv.x, urv[e],   hra); hrb = __builtin_fmaf(hv.y, urv[e],   hrb); \
        hna = __builtin_fmaf(hv.x, unv[e],   hna); hnb = __builtin_fmaf(hv.y, unv[e],   hnb); \
        hza = __builtin_fmaf(hv.z, uzv[e+1], hza); hzb = __builtin_fmaf(hv.w, uzv[e+1], hzb); \
        hra = __builtin_fmaf(hv.z, urv[e+1], hra); hrb = __builtin_fmaf(hv.w, urv[e+1], hrb); \
        hna = __builtin_fmaf(hv.z, unv[e+1], hna); hnb = __builtin_fmaf(hv.w, unv[e+1], hnb); } }
    DOTB(uz0, ur0, un0, 0)
    DOTB(uz1, ur1, un1, 16)
    DOTB(uz2, ur2, un2, 32)
    DOTB(uz3, ur3, un3, 48)
#undef DOTB
  }

  if (j == 0) {
    *(float2*)&out[NSAMP * NSTEP + s_base] = float2{logPa, logPb};
  }
}

extern "C" void kernel_launch(void* const* d_in, const int* in_sizes, int n_in,
                              void* d_out, int out_size, void* d_ws, size_t ws_size,
                              hipStream_t stream) {
  // inputs (setup_inputs order): nsamples(1), W(2x192), U(64x192), b(2x192),
  // Wd(64x2), bd(2) — float32
  const float* W  = (const float*)d_in[1];
  const float* U  = (const float*)d_in[2];
  const float* B  = (const float*)d_in[3];
  const float* Wd = (const float*)d_in[4];
  const float* Bd = (const float*)d_in[5];
  vmc_kernel<<<dim3(NSAMP / CPB), dim3(HID), 0, stream>>>(W, U, B, Wd, Bd, (float*)d_out);
}

// Round 15
// 489.013 us; speedup vs baseline: 1.7134x; 1.7134x over previous
//
#include <hip/hip_runtime.h>
#include <cstdint>
#include <math.h>

// GREEN since r6. Best = r12 529us. r13 (readlane) 650us and r14 (all-reg U ->
// AGPR accvgpr_read chains) 838us both PROVED: moving DS work to VALU loses;
// only deletions win. r14 also proved the difference-dense tail decision-safe
// (green, absmax 0.0).
// THIS ROUND = r12 dot (Uz/Ur in 128 real VGPRs + Un in LDS) + r14 diff-dense
// tail (butterfly 24->12 DS ops) + NEW: Un transposed into XOR-swizzled
// float4 rows unT4[j][c^(j&15)] -> 16 ds_read_b128 replace 64 ds_read_b32
// (~371->~192 DS cyc/step). Swizzled pattern = standard coalesced-b128 bank
// pattern (8 lanes/bank-quad, uniform; m134 ~12cyc). Values + FMA order
// bit-identical to r12/r14.
// EMPIRICAL RULES: only __launch_bounds__(64,1) gives the full reg budget
// ((64,2)->128 cap, r8 disaster); allocator grants ~180 VGPR, 128-reg U is
// safe; OccupancyPercent counter is gfx94x fallback (untrustworthy).
// Locked-in: PRNG = partitionable threefry (key_t = tf((0,42),(0,t)); bits =
// o0^o1 of tf(key_t,(0,2s+cat))); f32 in/out; out = [4096*144][4096];
// decisions rounding-robust (6 arithmetic variants, bit-identical streams).

#define NSAMP 4096
#define NSTEP 144
#define HID 64
#define CPB 2            // chains per block (one wave)

typedef float v16f __attribute__((ext_vector_type(16)));

// ---- JAX threefry2x32 (20 rounds, key-inject every 4) ----
__device__ __forceinline__ void threefry2x32(uint32_t k0, uint32_t k1,
                                             uint32_t x0, uint32_t x1,
                                             uint32_t& o0, uint32_t& o1) {
  const uint32_t ks0 = k0, ks1 = k1, ks2 = k0 ^ k1 ^ 0x1BD11BDAu;
  x0 += ks0; x1 += ks1;
#define TF_ROUND(d) { x0 += x1; x1 = (x1 << (d)) | (x1 >> (32 - (d))); x1 ^= x0; }
  TF_ROUND(13) TF_ROUND(15) TF_ROUND(26) TF_ROUND(6)
  x0 += ks1; x1 += ks2 + 1u;
  TF_ROUND(17) TF_ROUND(29) TF_ROUND(16) TF_ROUND(24)
  x0 += ks2; x1 += ks0 + 2u;
  TF_ROUND(13) TF_ROUND(15) TF_ROUND(26) TF_ROUND(6)
  x0 += ks0; x1 += ks1 + 3u;
  TF_ROUND(17) TF_ROUND(29) TF_ROUND(16) TF_ROUND(24)
  x0 += ks1; x1 += ks2 + 4u;
  TF_ROUND(13) TF_ROUND(15) TF_ROUND(26) TF_ROUND(6)
  x0 += ks2; x1 += ks0 + 5u;
#undef TF_ROUND
  o0 = x0; o1 = x1;
}

// fast branch-free f32 transcendentals (raw v_exp_f32 / v_log_f32 / v_rcp_f32)
__device__ __forceinline__ float fsig(float x) {        // 1/(1+e^-x), stable
  return __builtin_amdgcn_rcpf(1.0f + __expf(-x));
}
__device__ __forceinline__ float ftanh(float x) {       // 1 - 2/(e^2x+1)
  const float e = __expf(2.0f * x);
  return 1.0f - 2.0f * __builtin_amdgcn_rcpf(e + 1.0f);
}

__global__ __launch_bounds__(64, 1) void vmc_kernel(
    const float* __restrict__ W, const float* __restrict__ U,
    const float* __restrict__ B, const float* __restrict__ Wd,
    const float* __restrict__ Bd, float* __restrict__ out) {
  const int j = threadIdx.x;           // hidden unit owned by this lane
  const int s_base = blockIdx.x * CPB; // first of 2 chains in this block

  __shared__ __align__(16) float2 hsh2[HID];      // h[unit] = {chain a, chain b}
  __shared__ __align__(16) float4 unT4[HID * 16]; // Un^T, XOR-swizzled chunks
  __shared__ uint2 kkeys[NSTEP];
  __shared__ float gsh[CPB * 2 * NSTEP];          // gumbels [c*288 + 2t + cat]

  // --- per-step keys: key_t = threefry((0,42),(0,t)) ---
#pragma unroll 1
  for (int t = j; t < NSTEP; t += HID) {
    uint32_t o0, o1;
    threefry2x32(0u, 42u, 0u, (uint32_t)t, o0, o1);
    kkeys[t].x = o0; kkeys[t].y = o1;
  }
  // --- stage Un^T: lane j owns row j (Un column j), chunk c = k/4,
  // swizzled index c^(j&15). Global reads coalesced across lanes. ---
#pragma unroll 4
  for (int c = 0; c < 16; ++c) {
    float4 v;
    v.x = U[(4*c + 0) * 192 + 128 + j];
    v.y = U[(4*c + 1) * 192 + 128 + j];
    v.z = U[(4*c + 2) * 192 + 128 + j];
    v.w = U[(4*c + 3) * 192 + 128 + j];
    unT4[j * 16 + (c ^ (j & 15))] = v;
  }
  hsh2[j] = float2{0.0f, 0.0f};
  __syncthreads();

  // --- gumbels: EXACT path kept (f64 libm, one-time): bits = o0^o1 of
  // tf(key_t,(0,2s+cat)); u = bitcast(bits>>9|0x3f800000)-1 clamped tiny ---
#pragma unroll 1
  for (int id = j; id < CPB * 2 * NSTEP; id += HID) {
    const int c = id / 288;
    const int idx = id - c * 288;
    const uint2 kt = kkeys[idx >> 1];
    const uint32_t i = 2u * (uint32_t)(s_base + c) + (uint32_t)(idx & 1);
    uint32_t o0, o1;
    threefry2x32(kt.x, kt.y, 0u, i, o0, o1);
    const uint32_t bits = o0 ^ o1;
    union { uint32_t u; float f; } cv; cv.u = (bits >> 9) | 0x3F800000u;
    float uf = cv.f - 1.0f;
    uf = fmaxf(uf, 1.17549435e-38f);
    const float inner = (float)log((double)uf);
    gsh[id] = -(float)log((double)(-inner));
  }
  __syncthreads();

  // --- Uz, Ur columns for unit j: register-resident (128 floats, proven) ---
  v16f uz0, uz1, uz2, uz3, ur0, ur1, ur2, ur3;
#define LOADB(v, r, off) \
  { _Pragma("unroll") for (int e = 0; e < 16; ++e) v[e] = U[((r)*16 + e)*192 + (off) + j]; }
  LOADB(uz0, 0, 0)   LOADB(uz1, 1, 0)   LOADB(uz2, 2, 0)   LOADB(uz3, 3, 0)
  LOADB(ur0, 0, 64)  LOADB(ur1, 1, 64)  LOADB(ur2, 2, 64)  LOADB(ur3, 3, 64)
#undef LOADB

  const float b1z = B[192 + j], b1r = B[256 + j], b1n = B[320 + j];
  const float b0z = B[j],       b0r = B[64 + j],  b0n = B[128 + j];
  const float xW0z = W[j]       + b0z, xW1z = W[192 + j] + b0z;
  const float xW0r = W[64 + j]  + b0r, xW1r = W[256 + j] + b0r;
  const float xW0n = W[128 + j] + b0n, xW1n = W[320 + j] + b0n;
  const float wdd = Wd[2*j + 1] - Wd[2*j];   // dense difference column
  const float bdd = Bd[1] - Bd[0];
  const int swz = j & 15;

  float ha = 0.0f, hb_ = 0.0f;
  float logPa = 0.0f, logPb = 0.0f;
  float axz = b0z, axr = b0r, axn = b0n;  // t=0: x=0 -> xm = b[0]
  float bxz = b0z, bxr = b0r, bxn = b0n;
  // loop-carried dot accumulators; h_{-1}=0 -> dot=0 for t=0
  float hza = 0.f, hzb = 0.f, hra = 0.f, hrb = 0.f, hna = 0.f, hnb = 0.f;

  for (int t = 0; t < NSTEP; ++t) {
    // ---- gates from the PREVIOUS iteration's dot (software pipeline) ----
    {
      const float az = axz + (hza + b1z), ar = axr + (hra + b1r);
      const float zz = fsig(az), rr = fsig(ar);
      const float hh = ftanh(axn + rr * (hna + b1n));
      ha = zz * ha + (1.0f - zz) * hh;
    }
    {
      const float az = bxz + (hzb + b1z), ar = bxr + (hrb + b1r);
      const float zz = fsig(az), rr = fsig(ar);
      const float hh = ftanh(bxn + rr * (hnb + b1n));
      hb_ = zz * hb_ + (1.0f - zz) * hh;
    }
    hsh2[j] = float2{ha, hb_};   // single wave: LDS ops in program order

    // ---- dense: single difference-reduction per chain (r14-proven) ----
    float da = ha * wdd, db = hb_ * wdd;
#pragma unroll
    for (int m = 1; m < 64; m <<= 1) {
      da += __shfl_xor(da, m, 64);
      db += __shfl_xor(db, m, 64);
    }
    int sma, smb;
    {
      const float d = da + bdd;
      const float p1 = fsig(d), p0 = fsig(-d);
      const float lp0 = __logf(1e-10f + p0);
      const float lp1 = __logf(1e-10f + p1);
      const float g0 = gsh[2*t], g1 = gsh[2*t + 1];
      sma = (lp1 + g1) > (lp0 + g0);
      logPa += sma ? lp1 : lp0;
      axz = sma ? xW1z : xW0z;
      axr = sma ? xW1r : xW0r;
      axn = sma ? xW1n : xW0n;
    }
    {
      const float d = db + bdd;
      const float p1 = fsig(d), p0 = fsig(-d);
      const float lp0 = __logf(1e-10f + p0);
      const float lp1 = __logf(1e-10f + p1);
      const float g0 = gsh[288 + 2*t], g1 = gsh[288 + 2*t + 1];
      smb = (lp1 + g1) > (lp0 + g0);
      logPb += smb ? lp1 : lp0;
      bxz = smb ? xW1z : xW0z;
      bxr = smb ? xW1r : xW0r;
      bxn = smb ? xW1n : xW0n;
    }
    if (j == 0) {
      out[(s_base + 0) * NSTEP + t] = sma ? 1.0f : 0.0f;
      out[(s_base + 1) * NSTEP + t] = smb ? 1.0f : 0.0f;
    }

    // ---- dot for NEXT step: hm = h_t @ U, k-ascending FMA from 0.
    // h via uniform b128 broadcast; Un via swizzled per-lane b128 rows.
    // Same values, same order as r12/r14 -> bit-identical decisions. ----
    hza = 0.f; hzb = 0.f; hra = 0.f; hrb = 0.f; hna = 0.f; hnb = 0.f;
#define DOTC(uzv, urv, blk, cc) \
    { const int c_ = (blk)*4 + (cc); \
      const float4 hA = *(const float4*)&hsh2[c_*4]; \
      const float4 hB = *(const float4*)&hsh2[c_*4 + 2]; \
      const float4 uv = unT4[j*16 + (c_ ^ swz)]; \
      const int e_ = (cc)*4; \
      hza = __builtin_fmaf(hA.x, uzv[e_+0], hza); hzb = __builtin_fmaf(hA.y, uzv[e_+0], hzb); \
      hra = __builtin_fmaf(hA.x, urv[e_+0], hra); hrb = __builtin_fmaf(hA.y, urv[e_+0], hrb); \
      hna = __builtin_fmaf(hA.x, uv.x,      hna); hnb = __builtin_fmaf(hA.y, uv.x,      hnb); \
      hza = __builtin_fmaf(hA.z, uzv[e_+1], hza); hzb = __builtin_fmaf(hA.w, uzv[e_+1], hzb); \
      hra = __builtin_fmaf(hA.z, urv[e_+1], hra); hrb = __builtin_fmaf(hA.w, urv[e_+1], hrb); \
      hna = __builtin_fmaf(hA.z, uv.y,      hna); hnb = __builtin_fmaf(hA.w, uv.y,      hnb); \
      hza = __builtin_fmaf(hB.x, uzv[e_+2], hza); hzb = __builtin_fmaf(hB.y, uzv[e_+2], hzb); \
      hra = __builtin_fmaf(hB.x, urv[e_+2], hra); hrb = __builtin_fmaf(hB.y, urv[e_+2], hrb); \
      hna = __builtin_fmaf(hB.x, uv.z,      hna); hnb = __builtin_fmaf(hB.y, uv.z,      hnb); \
      hza = __builtin_fmaf(hB.z, uzv[e_+3], hza); hzb = __builtin_fmaf(hB.w, uzv[e_+3], hzb); \
      hra = __builtin_fmaf(hB.z, urv[e_+3], hra); hrb = __builtin_fmaf(hB.w, urv[e_+3], hrb); \
      hna = __builtin_fmaf(hB.z, uv.w,      hna); hnb = __builtin_fmaf(hB.w, uv.w,      hnb); }
#define DOTBLK(uzv, urv, blk) \
    DOTC(uzv, urv, blk, 0) DOTC(uzv, urv, blk, 1) DOTC(uzv, urv, blk, 2) DOTC(uzv, urv, blk, 3)
    DOTBLK(uz0, ur0, 0)
    DOTBLK(uz1, ur1, 1)
    DOTBLK(uz2, ur2, 2)
    DOTBLK(uz3, ur3, 3)
#undef DOTBLK
#undef DOTC
  }

  if (j == 0) {
    *(float2*)&out[NSAMP * NSTEP + s_base] = float2{logPa, logPb};
  }
}

extern "C" void kernel_launch(void* const* d_in, const int* in_sizes, int n_in,
                              void* d_out, int out_size, void* d_ws, size_t ws_size,
                              hipStream_t stream) {
  // inputs (setup_inputs order): nsamples(1), W(2x192), U(64x192), b(2x192),
  // Wd(64x2), bd(2) — float32
  const float* W  = (const float*)d_in[1];
  const float* U  = (const float*)d_in[2];
  const float* B  = (const float*)d_in[3];
  const float* Wd = (const float*)d_in[4];
  const float* Bd = (const float*)d_in[5];
  vmc_kernel<<<dim3(NSAMP / CPB), dim3(HID), 0, stream>>>(W, U, B, Wd, Bd, (float*)d_out);
}